// Round 1
// baseline (433.048 us; speedup 1.0000x reference)
//
#include <hip/hip_runtime.h>

// Caps_Layer: x[1024,512,120] f32, W[120,25] f32 -> out[1024,5,5] f32
// Fused: per-block batch element; u_hat kept in registers (2 rows/thread);
// 4 routing iterations with shuffle+LDS block reduction of the 25-value s.

#define NCAP 5
#define DCAP 5
#define NOUT 25      // NCAP*DCAP
#define DIN 120
#define SEQ 512
#define ROUTINGS 4

__global__ __launch_bounds__(256) void caps_kernel(
    const float* __restrict__ x,   // [batch, 512, 120]
    const float* __restrict__ W,   // [120, 25]
    float* __restrict__ out)       // [batch, 5, 5]
{
    const int b    = blockIdx.x;
    const int t    = threadIdx.x;   // 0..255
    const int lane = t & 63;
    const int wv   = t >> 6;

    __shared__ float red[4][NOUT];

    // ---------- GEMM phase: u_hat for rows i0=2t, i1=2t+1 ----------
    float acc[2][NOUT];
#pragma unroll
    for (int r = 0; r < 2; ++r)
#pragma unroll
        for (int j = 0; j < NOUT; ++j) acc[r][j] = 0.f;

    const float* xb = x + (size_t)b * SEQ * DIN;
#pragma unroll
    for (int r = 0; r < 2; ++r) {
        const float4* xp = (const float4*)(xb + (2 * t + r) * DIN);
        // k loop in float4 steps; W indices are wave-uniform -> s_load
        for (int u = 0; u < DIN / 4; ++u) {
            float4 v = xp[u];
            const float* wr = W + u * 4 * NOUT;
#pragma unroll
            for (int j = 0; j < NOUT; ++j) {
                float a = acc[r][j];
                a = fmaf(v.x, wr[j],          a);
                a = fmaf(v.y, wr[j + NOUT],   a);
                a = fmaf(v.z, wr[j + 2*NOUT], a);
                a = fmaf(v.w, wr[j + 3*NOUT], a);
                acc[r][j] = a;
            }
        }
    }

    // ---------- Routing phase ----------
    float bb[2][NCAP];              // logits for the 2 owned rows
#pragma unroll
    for (int r = 0; r < 2; ++r)
#pragma unroll
        for (int c = 0; c < NCAP; ++c) bb[r][c] = 0.f;

    float o[NOUT];                  // squashed outputs (replicated per thread)

    for (int it = 0; it < ROUTINGS; ++it) {
        // per-thread partial of s[j][k] = sum_i c[j,i] * u_hat[j,i,k]
        float p[NOUT];
#pragma unroll
        for (int j = 0; j < NOUT; ++j) p[j] = 0.f;

#pragma unroll
        for (int r = 0; r < 2; ++r) {
            // softmax over capsules of bb[r][:]
            float m = bb[r][0];
#pragma unroll
            for (int c = 1; c < NCAP; ++c) m = fmaxf(m, bb[r][c]);
            float e[NCAP]; float se = 0.f;
#pragma unroll
            for (int c = 0; c < NCAP; ++c) { e[c] = __expf(bb[r][c] - m); se += e[c]; }
            float inv = 1.f / se;
#pragma unroll
            for (int c = 0; c < NCAP; ++c) {
                float cc = e[c] * inv;
#pragma unroll
                for (int k = 0; k < DCAP; ++k)
                    p[c*DCAP + k] = fmaf(cc, acc[r][c*DCAP + k], p[c*DCAP + k]);
            }
        }

        // block reduction of 25 partials: 64-lane butterfly, then 4 waves via LDS
#pragma unroll
        for (int d = 1; d < 64; d <<= 1)
#pragma unroll
            for (int j = 0; j < NOUT; ++j) p[j] += __shfl_xor(p[j], d, 64);

        if (lane == 0) {
#pragma unroll
            for (int j = 0; j < NOUT; ++j) red[wv][j] = p[j];
        }
        __syncthreads();
        float s[NOUT];
#pragma unroll
        for (int j = 0; j < NOUT; ++j)
            s[j] = red[0][j] + red[1][j] + red[2][j] + red[3][j];
        __syncthreads();   // red[] reused next iteration

        // squash: s / sqrt(|s|^2 + eps) per capsule
#pragma unroll
        for (int c = 0; c < NCAP; ++c) {
            float ss = 0.f;
#pragma unroll
            for (int k = 0; k < DCAP; ++k)
                ss = fmaf(s[c*DCAP + k], s[c*DCAP + k], ss);
            float sc = rsqrtf(ss + 1e-7f);
#pragma unroll
            for (int k = 0; k < DCAP; ++k) o[c*DCAP + k] = s[c*DCAP + k] * sc;
        }

        // agreement update: b[j,i] = sum_k o[j,k] * u_hat[j,i,k]  (overwrite)
        if (it < ROUTINGS - 1) {
#pragma unroll
            for (int r = 0; r < 2; ++r)
#pragma unroll
                for (int c = 0; c < NCAP; ++c) {
                    float d0 = 0.f;
#pragma unroll
                    for (int k = 0; k < DCAP; ++k)
                        d0 = fmaf(o[c*DCAP + k], acc[r][c*DCAP + k], d0);
                    bb[r][c] = d0;
                }
        }
    }

    if (t < NOUT) out[(size_t)b * NOUT + t] = o[t];
}

extern "C" void kernel_launch(void* const* d_in, const int* in_sizes, int n_in,
                              void* d_out, int out_size, void* d_ws, size_t ws_size,
                              hipStream_t stream) {
    const float* x   = (const float*)d_in[0];
    const float* W   = (const float*)d_in[1];
    float*       o   = (float*)d_out;
    const int batch  = in_sizes[0] / (SEQ * DIN);   // 1024
    caps_kernel<<<dim3(batch), dim3(256), 0, stream>>>(x, W, o);
}

// Round 2
// 401.525 us; speedup vs baseline: 1.0785x; 1.0785x over previous
//
#include <hip/hip_runtime.h>

// Caps_Layer: x[1024,512,120] f32, W[120,25] f32 -> out[1024,5,5] f32
// Round 2: coalesced global->LDS K-tile staging (fixes the 960B-stride gather
// that capped round 1 at 920 GB/s). u_hat stays in registers (2 rows/thread);
// W read via wave-uniform indexing -> scalar loads; routing phase unchanged.

#define NCAP 5
#define DCAP 5
#define NOUT 25      // NCAP*DCAP
#define DIN 120
#define SEQ 512
#define ROUTINGS 4

#define KT   24      // K-tile size (120 = 5*24)
#define PAD  26      // padded LDS row stride in floats (even -> b64 aligned;
                     // bank starts (20t)%32 cover all banks -> conflict-free)

__global__ __launch_bounds__(256) void caps_kernel(
    const float* __restrict__ x,   // [batch, 512, 120]
    const float* __restrict__ W,   // [120, 25]
    float* __restrict__ out)       // [batch, 5, 5]
{
    const int b    = blockIdx.x;
    const int t    = threadIdx.x;   // 0..255
    const int lane = t & 63;
    const int wv   = t >> 6;

    __shared__ float xt[SEQ * PAD];        // 53,248 B
    __shared__ float red[4][NOUT];

    const float* xb = x + (size_t)b * SEQ * DIN;

    float acc[2][NOUT];
#pragma unroll
    for (int r = 0; r < 2; ++r)
#pragma unroll
        for (int j = 0; j < NOUT; ++j) acc[r][j] = 0.f;

    const int r0 = (2 * t) * PAD;          // LDS float offset of row 2t
    const int r1 = (2 * t + 1) * PAD;      // row 2t+1 (even: 26 even)

    // ---------- GEMM phase: 5 K-tiles of 24 ----------
    for (int tile = 0; tile < 5; ++tile) {
        const int k0 = tile * KT;

        // coalesced staging: 512 rows x 6 float4 = 3072 float4, 12/thread
#pragma unroll
        for (int i = 0; i < 12; ++i) {
            int f   = t + 256 * i;
            int row = f / 6;
            int q   = f - row * 6;         // f % 6
            float4 v = *(const float4*)(xb + row * DIN + k0 + 4 * q);
            float* dst = &xt[row * PAD + 4 * q];
            *(float2*)(dst)     = make_float2(v.x, v.y);
            *(float2*)(dst + 2) = make_float2(v.z, v.w);
        }
        __syncthreads();

        // compute from LDS: 6 k-quads
#pragma unroll
        for (int u = 0; u < 6; ++u) {
            float2 a0 = *(const float2*)&xt[r0 + 4 * u];
            float2 a1 = *(const float2*)&xt[r0 + 4 * u + 2];
            float2 b0 = *(const float2*)&xt[r1 + 4 * u];
            float2 b1 = *(const float2*)&xt[r1 + 4 * u + 2];
            const float* wr = W + (k0 + 4 * u) * NOUT;   // wave-uniform -> s_load
#pragma unroll
            for (int j = 0; j < NOUT; ++j) {
                float w0 = wr[j];
                float w1 = wr[j + NOUT];
                float w2 = wr[j + 2 * NOUT];
                float w3 = wr[j + 3 * NOUT];
                acc[0][j] = fmaf(a1.y, w3, fmaf(a1.x, w2, fmaf(a0.y, w1, fmaf(a0.x, w0, acc[0][j]))));
                acc[1][j] = fmaf(b1.y, w3, fmaf(b1.x, w2, fmaf(b0.y, w1, fmaf(b0.x, w0, acc[1][j]))));
            }
        }
        __syncthreads();   // xt reused next tile
    }

    // ---------- Routing phase ----------
    float bb[2][NCAP];
#pragma unroll
    for (int r = 0; r < 2; ++r)
#pragma unroll
        for (int c = 0; c < NCAP; ++c) bb[r][c] = 0.f;

    float o[NOUT];

    for (int it = 0; it < ROUTINGS; ++it) {
        float p[NOUT];
#pragma unroll
        for (int j = 0; j < NOUT; ++j) p[j] = 0.f;

#pragma unroll
        for (int r = 0; r < 2; ++r) {
            float m = bb[r][0];
#pragma unroll
            for (int c = 1; c < NCAP; ++c) m = fmaxf(m, bb[r][c]);
            float e[NCAP]; float se = 0.f;
#pragma unroll
            for (int c = 0; c < NCAP; ++c) { e[c] = __expf(bb[r][c] - m); se += e[c]; }
            float inv = 1.f / se;
#pragma unroll
            for (int c = 0; c < NCAP; ++c) {
                float cc = e[c] * inv;
#pragma unroll
                for (int k = 0; k < DCAP; ++k)
                    p[c*DCAP + k] = fmaf(cc, acc[r][c*DCAP + k], p[c*DCAP + k]);
            }
        }

        // block reduction: 64-lane butterfly, then 4 waves via LDS
#pragma unroll
        for (int d = 1; d < 64; d <<= 1)
#pragma unroll
            for (int j = 0; j < NOUT; ++j) p[j] += __shfl_xor(p[j], d, 64);

        if (lane == 0) {
#pragma unroll
            for (int j = 0; j < NOUT; ++j) red[wv][j] = p[j];
        }
        __syncthreads();
        float s[NOUT];
#pragma unroll
        for (int j = 0; j < NOUT; ++j)
            s[j] = red[0][j] + red[1][j] + red[2][j] + red[3][j];
        __syncthreads();

        // squash per capsule
#pragma unroll
        for (int c = 0; c < NCAP; ++c) {
            float ss = 0.f;
#pragma unroll
            for (int k = 0; k < DCAP; ++k)
                ss = fmaf(s[c*DCAP + k], s[c*DCAP + k], ss);
            float sc = rsqrtf(ss + 1e-7f);
#pragma unroll
            for (int k = 0; k < DCAP; ++k) o[c*DCAP + k] = s[c*DCAP + k] * sc;
        }

        if (it < ROUTINGS - 1) {
#pragma unroll
            for (int r = 0; r < 2; ++r)
#pragma unroll
                for (int c = 0; c < NCAP; ++c) {
                    float d0 = 0.f;
#pragma unroll
                    for (int k = 0; k < DCAP; ++k)
                        d0 = fmaf(o[c*DCAP + k], acc[r][c*DCAP + k], d0);
                    bb[r][c] = d0;
                }
        }
    }

    if (t < NOUT) out[(size_t)b * NOUT + t] = o[t];
}

extern "C" void kernel_launch(void* const* d_in, const int* in_sizes, int n_in,
                              void* d_out, int out_size, void* d_ws, size_t ws_size,
                              hipStream_t stream) {
    const float* x   = (const float*)d_in[0];
    const float* W   = (const float*)d_in[1];
    float*       o   = (float*)d_out;
    const int batch  = in_sizes[0] / (SEQ * DIN);   // 1024
    caps_kernel<<<dim3(batch), dim3(256), 0, stream>>>(x, W, o);
}